// Round 9
// baseline (4649.563 us; speedup 1.0000x reference)
//
#include <hip/hip_runtime.h>
#include <math.h>

// Grid-RNN (WhileOpGridLSTMNet): DEPTH=2, SRC=TRG=32, B=32, H=256
// out[d][i][j][c][b][h], c=0:HX, c=1:HY
#define SRCN 32
#define TRGN 32
#define BN   32
#define HN   256
#define BH   (BN*HN)          // 8192 floats per (cell,channel)
#define CELL (2*BH)           // 16384 floats per cell
#define DSZ  ((size_t)SRCN*TRGN*CELL) // floats per depth
#define NRB  4                // b-rows per chain block
#define NBS  8                // b-slices

__host__ __device__ __forceinline__ int ncd(int t) { // cells on diag t (0..62)
    int a = t + 1, b = 63 - t;
    int m = a < b ? a : b;
    return m < 32 ? m : 32;
}

// Flag test via atomic RMW: executes at the coherence point (L3) -> immune to
// stale per-XCD L2 (the round-3 relaxed-load deadlock). Bounded: never hangs.
__device__ __forceinline__ void spinwait(int* p) {
    for (int n = 0; n < (1 << 22); ++n) {
        if (__hip_atomic_fetch_add(p, 0, __ATOMIC_ACQUIRE, __HIP_MEMORY_SCOPE_AGENT) > 0)
            return;
        __builtin_amdgcn_s_sleep(8);
    }
}
// Cross-block state traffic: agent-scope relaxed atomics (sc1) -> write-through
// to L3 / read from L3. No threadfence => no L2 writeback/invalidate thrash.
__device__ __forceinline__ float cldf(const float* p) {
    return __hip_atomic_load(p, __ATOMIC_RELAXED, __HIP_MEMORY_SCOPE_AGENT);
}
__device__ __forceinline__ void cstf(float* p, float v) {
    __hip_atomic_store(p, v, __ATOMIC_RELAXED, __HIP_MEMORY_SCOPE_AGENT);
}

// ---------------------------------------------------------------------------
// proj0 (proven): xp0[i]=source[i]@W0 ; yp0[j]=target[j]@W0   (into ws)
// ---------------------------------------------------------------------------
__global__ __launch_bounds__(256) void proj0_kernel(
    const float* __restrict__ src, const float* __restrict__ trg,
    const float* __restrict__ W0, float* __restrict__ Xp0, float* __restrict__ Yp0)
{
    __shared__ float xs[BH];
    int blk = blockIdx.x >> 2, tile = blockIdx.x & 3;
    const float* X; float* P;
    if (blk < SRCN) { X = src + blk * BH; P = Xp0 + blk * BH; }
    else            { X = trg + (blk - SRCN) * BH; P = Yp0 + (blk - SRCN) * BH; }
    int tid = threadIdx.x;
    { const float4* x4 = (const float4*)X; float4* s4 = (float4*)xs;
#pragma unroll
      for (int r = 0; r < 8; ++r) s4[tid + r * 256] = x4[tid + r * 256]; }
    __syncthreads();
    int h = tile * 64 + (tid & 63), bg = tid >> 6;
    float acc[8] = {0,0,0,0,0,0,0,0};
    for (int k = 0; k < HN; k += 4) {
        float w0 = W0[(k+0)*HN+h], w1 = W0[(k+1)*HN+h], w2 = W0[(k+2)*HN+h], w3 = W0[(k+3)*HN+h];
#pragma unroll
        for (int bb = 0; bb < 8; ++bb) {
            int b = bg * 8 + bb;
            float4 xv = *(const float4*)&xs[b * HN + k];
            acc[bb] += xv.x*w0 + xv.y*w1 + xv.z*w2 + xv.w*w3;
        }
    }
#pragma unroll
    for (int bb = 0; bb < 8; ++bb) P[(bg*8+bb)*HN + h] = acc[bb];
}

// ---------------------------------------------------------------------------
// chain_kernel: ONE dispatch for both layers.
// block = (L, i, bslice): sweeps j=0..31. j-neighbor state lives in LDS
// (own previous output); i-neighbor fetched from global after flag.
// proj1 folded into layer-1 cells (xp1/yp1 never hit memory).
// Deps acyclic in blockIdx; 512 blocks all resident at 2 blocks/CU.
// ---------------------------------------------------------------------------
__global__ __launch_bounds__(256, 2) void chain_kernel(
    const float* __restrict__ W, const float* __restrict__ U,
    const float* __restrict__ bias, float* __restrict__ out,
    const float* __restrict__ xp0, const float* __restrict__ yp0,
    int* __restrict__ flg)
{
    __shared__ __align__(16) float sPrev[NRB][HN]; // own HX[i][j-1]
    __shared__ __align__(16) float sUp[NRB][HN];   // HX[i-1][j]
    __shared__ __align__(16) float sX0[NRB][HN];   // l1: HX0[i][j]
    __shared__ __align__(16) float sY0[NRB][HN];   // l1: HY0[i][j]

    const int blk = blockIdx.x;     // 0..511
    const int L   = blk >> 8;       // layer
    const int i   = (blk >> 3) & 31;
    const int bs  = blk & 7;
    const int r0  = bs * NRB;
    const int h   = threadIdx.x;    // 0..255 = h column

    const float* Ux = U + (size_t)L * 131072 + h; // col h, stride HN over k
    const float* Uy = Ux + 65536;
    const float* W1 = W + 65536 + h;
    const float bv  = bias[L * HN + h];
    float* outL = out + (size_t)L * DSZ;

#pragma unroll
    for (int b = 0; b < NRB; ++b) sPrev[b][h] = 0.f;

    for (int j = 0; j < TRGN; ++j) {
        const int cell = i * TRGN + j;

        // ---- wait for producers (one spinner), then stage ----
        if (h == 0) {
            if (i > 0)  spinwait(&flg[((L * 32 + i - 1) * 32 + j) * NBS + bs]);
            if (L == 1) spinwait(&flg[(i * 32 + j) * NBS + bs]); // layer-0 same cell
        }
        __syncthreads();
        if (i > 0) {
            const float* up = outL + (size_t)((i - 1) * TRGN + j) * CELL
                            + (size_t)r0 * HN + h;
#pragma unroll
            for (int b = 0; b < NRB; ++b) sUp[b][h] = cldf(up + b * HN);
        }
        if (L == 1) {
            const float* x0 = out + (size_t)cell * CELL + (size_t)r0 * HN + h;
#pragma unroll
            for (int b = 0; b < NRB; ++b) {
                sX0[b][h] = cldf(x0 + b * HN);
                sY0[b][h] = cldf(x0 + BH + b * HN);
            }
        }
        __syncthreads();

        // ---- recurrence GEMMs: acc = sUp@Ux + sPrev@Uy ----
        float acc[NRB] = {0.f, 0.f, 0.f, 0.f};
        if (i > 0) {
            for (int k = 0; k < HN; k += 4) {
                float w0 = Ux[(k+0)*HN], w1 = Ux[(k+1)*HN];
                float w2 = Ux[(k+2)*HN], w3 = Ux[(k+3)*HN];
#pragma unroll
                for (int b = 0; b < NRB; ++b) {
                    float4 s = *(const float4*)&sUp[b][k];   // LDS broadcast
                    acc[b] += s.x*w0 + s.y*w1 + s.z*w2 + s.w*w3;
                }
            }
        }
        for (int k = 0; k < HN; k += 4) {
            float w0 = Uy[(k+0)*HN], w1 = Uy[(k+1)*HN];
            float w2 = Uy[(k+2)*HN], w3 = Uy[(k+3)*HN];
#pragma unroll
            for (int b = 0; b < NRB; ++b) {
                float4 s = *(const float4*)&sPrev[b][k];     // LDS broadcast
                acc[b] += s.x*w0 + s.y*w1 + s.z*w2 + s.w*w3;
            }
        }

        // ---- inputs xp/yp and tanh epilogue ----
        float hx[NRB], hy[NRB];
        if (L == 0) {
            const float* xr = xp0 + (size_t)i * BH + (size_t)r0 * HN + h;
            const float* yr = yp0 + (size_t)j * BH + (size_t)r0 * HN + h;
#pragma unroll
            for (int b = 0; b < NRB; ++b) {
                float tmp = acc[b] + bv;
                hx[b] = tanhf(xr[b * HN] + tmp);
                hy[b] = tanhf(yr[b * HN] + tmp);
            }
        } else {
            // folded proj1: aX = HX0@W1, aY = HY0@W1 (shared W1 loads)
            float aX[NRB] = {0.f, 0.f, 0.f, 0.f};
            float aY[NRB] = {0.f, 0.f, 0.f, 0.f};
            for (int k = 0; k < HN; k += 4) {
                float w0 = W1[(k+0)*HN], w1 = W1[(k+1)*HN];
                float w2 = W1[(k+2)*HN], w3 = W1[(k+3)*HN];
#pragma unroll
                for (int b = 0; b < NRB; ++b) {
                    float4 sx4 = *(const float4*)&sX0[b][k];
                    float4 sy4 = *(const float4*)&sY0[b][k];
                    aX[b] += sx4.x*w0 + sx4.y*w1 + sx4.z*w2 + sx4.w*w3;
                    aY[b] += sy4.x*w0 + sy4.y*w1 + sy4.z*w2 + sy4.w*w3;
                }
            }
#pragma unroll
            for (int b = 0; b < NRB; ++b) {
                float tmp = acc[b] + bv;
                hx[b] = tanhf(aX[b] + tmp);
                hy[b] = tanhf(aY[b] + tmp);
            }
        }

        __syncthreads();  // everyone done READING sPrev before overwrite
        float* ox = outL + (size_t)cell * CELL + (size_t)r0 * HN + h;
#pragma unroll
        for (int b = 0; b < NRB; ++b) {
            cstf(ox + b * HN, hx[b]);         // sc1: lands at L3
            cstf(ox + BH + b * HN, hy[b]);
            sPrev[b][h] = hx[b];              // j-neighbor for next cell
        }
        __syncthreads();  // all threads' stores drained (vmcnt 0) before flag
        if (h == 0)
            __hip_atomic_fetch_add(&flg[((L * 32 + i) * 32 + j) * NBS + bs], 1,
                                   __ATOMIC_RELEASE, __HIP_MEMORY_SCOPE_AGENT);
    }
}

// ===========================================================================
// Fallback (round-1 ladder, proven): used only if ws_size is too small.
// ===========================================================================
__global__ __launch_bounds__(256) void proj1_kernel(
    float* __restrict__ out, const float* __restrict__ W1)
{
    __shared__ float hxs[BH];
    __shared__ float hys[BH];
    int cell = blockIdx.x >> 2, tile = blockIdx.x & 3;
    const float* hx0 = out + (size_t)cell * CELL;
    const float* hy0 = hx0 + BH;
    float* xp1 = out + DSZ + (size_t)cell * CELL;
    float* yp1 = xp1 + BH;
    int tid = threadIdx.x;
    { const float4* a4 = (const float4*)hx0; const float4* b4 = (const float4*)hy0;
      float4* sa = (float4*)hxs; float4* sb = (float4*)hys;
#pragma unroll
      for (int r = 0; r < 8; ++r) { sa[tid+r*256] = a4[tid+r*256]; sb[tid+r*256] = b4[tid+r*256]; } }
    __syncthreads();
    int h = tile * 64 + (tid & 63), bg = tid >> 6;
    float ax[8] = {0,0,0,0,0,0,0,0}, ay[8] = {0,0,0,0,0,0,0,0};
    for (int k = 0; k < HN; k += 4) {
        float w0 = W1[(k+0)*HN+h], w1 = W1[(k+1)*HN+h], w2 = W1[(k+2)*HN+h], w3 = W1[(k+3)*HN+h];
#pragma unroll
        for (int bb = 0; bb < 8; ++bb) {
            int b = bg * 8 + bb;
            float4 xv = *(const float4*)&hxs[b*HN+k];
            float4 yv = *(const float4*)&hys[b*HN+k];
            ax[bb] += xv.x*w0 + xv.y*w1 + xv.z*w2 + xv.w*w3;
            ay[bb] += yv.x*w0 + yv.y*w1 + yv.z*w2 + yv.w*w3;
        }
    }
#pragma unroll
    for (int bb = 0; bb < 8; ++bb) {
        int b = bg * 8 + bb;
        xp1[b*HN+h] = ax[bb]; yp1[b*HN+h] = ay[bb];
    }
}

__global__ __launch_bounds__(256) void diag_kernel(
    float* out, const float* __restrict__ U, const float* __restrict__ bias,
    const float* __restrict__ Xp0, const float* __restrict__ Yp0, int d, int t)
{
    __shared__ float sxs[BH];
    __shared__ float phs[BH];
    int c = blockIdx.x >> 2, tile = blockIdx.x & 3;
    int i0 = t - (TRGN - 1); if (i0 < 0) i0 = 0;
    int i = i0 + c, j = t - i;
    const float* Ux = U + d * (2 * HN * HN);
    const float* Uy = Ux + HN * HN;
    float* outD = out + (size_t)d * DSZ;
    const float* sx = (i > 0) ? outD + (size_t)((i-1)*TRGN + j) * CELL : nullptr;
    const float* ph = (j > 0) ? outD + (size_t)(i*TRGN + (j-1)) * CELL : nullptr;
    float* oHX = outD + (size_t)(i*TRGN + j) * CELL;
    float* oHY = oHX + BH;
    const float* xp = d ? oHX : (Xp0 + i * BH);
    const float* yp = d ? oHY : (Yp0 + j * BH);
    const float* bd = bias + d * HN;
    int tid = threadIdx.x;
    { const float4* s4 = (const float4*)sx; const float4* p4 = (const float4*)ph;
      float4* d1 = (float4*)sxs; float4* d2 = (float4*)phs;
      float4 z = make_float4(0.f,0.f,0.f,0.f);
#pragma unroll
      for (int r = 0; r < 8; ++r) { int idx = tid + r*256; d1[idx] = sx ? s4[idx] : z; d2[idx] = ph ? p4[idx] : z; } }
    __syncthreads();
    int h = tile * 64 + (tid & 63), bg = tid >> 6;
    float acc[8] = {0,0,0,0,0,0,0,0};
    for (int k = 0; k < HN; k += 4) {
        float ux0 = Ux[(k+0)*HN+h], ux1 = Ux[(k+1)*HN+h], ux2 = Ux[(k+2)*HN+h], ux3 = Ux[(k+3)*HN+h];
        float uy0 = Uy[(k+0)*HN+h], uy1 = Uy[(k+1)*HN+h], uy2 = Uy[(k+2)*HN+h], uy3 = Uy[(k+3)*HN+h];
#pragma unroll
        for (int bb = 0; bb < 8; ++bb) {
            int b = bg * 8 + bb;
            float4 sv = *(const float4*)&sxs[b*HN+k];
            float4 pv = *(const float4*)&phs[b*HN+k];
            acc[bb] += sv.x*ux0 + sv.y*ux1 + sv.z*ux2 + sv.w*ux3
                     + pv.x*uy0 + pv.y*uy1 + pv.z*uy2 + pv.w*uy3;
        }
    }
    float bv = bd[h];
#pragma unroll
    for (int bb = 0; bb < 8; ++bb) {
        int b = bg * 8 + bb;
        float temp = acc[bb] + bv;
        oHX[b*HN+h] = tanhf(xp[b*HN+h] + temp);
        oHY[b*HN+h] = tanhf(yp[b*HN+h] + temp);
    }
}

// ===========================================================================
extern "C" void kernel_launch(void* const* d_in, const int* in_sizes, int n_in,
                              void* d_out, int out_size, void* d_ws, size_t ws_size,
                              hipStream_t stream)
{
    const float* source = (const float*)d_in[0];
    const float* target = (const float*)d_in[1];
    const float* W      = (const float*)d_in[2]; // [2][256][256]
    const float* U      = (const float*)d_in[3]; // [2][512][256]
    const float* bias   = (const float*)d_in[4]; // [2][1][256]
    float* out = (float*)d_out;

    // ws layout: xp0 [1MB] | yp0 [1MB] | flags [32KB]
    const size_t need = 2u * 1024 * 1024 + 32768;
    if (d_ws != nullptr && ws_size >= need) {
        float* xp0 = (float*)d_ws;
        float* yp0 = xp0 + 32 * BH;
        int*   flg = (int*)(yp0 + 32 * BH);
        hipMemsetAsync(flg, 0, 2 * 32 * 32 * NBS * sizeof(int), stream);
        proj0_kernel<<<dim3(64 * 4), dim3(256), 0, stream>>>(source, target, W, xp0, yp0);
        chain_kernel<<<dim3(512), dim3(256), 0, stream>>>(W, U, bias, out, xp0, yp0, flg);
    } else {
        // Proven round-1 ladder (scratch aliased into out[1] region; safe
        // because proj1 runs only after ALL layer-0 diagonals).
        float* Xp0 = out + DSZ;
        float* Yp0 = Xp0 + SRCN * BH;
        proj0_kernel<<<dim3(64 * 4), dim3(256), 0, stream>>>(source, target, W, Xp0, Yp0);
        for (int t = 0; t < SRCN + TRGN - 1; ++t) {
            int nc = ncd(t);
            diag_kernel<<<dim3(nc * 4), dim3(256), 0, stream>>>(out, U, bias, Xp0, Yp0, 0, t);
        }
        proj1_kernel<<<dim3(1024 * 4), dim3(256), 0, stream>>>(out, W + HN * HN);
        for (int t = 0; t < SRCN + TRGN - 1; ++t) {
            int nc = ncd(t);
            diag_kernel<<<dim3(nc * 4), dim3(256), 0, stream>>>(out, U, bias, nullptr, nullptr, 1, t);
        }
    }
}

// Round 10
// 2688.758 us; speedup vs baseline: 1.7293x; 1.7293x over previous
//
#include <hip/hip_runtime.h>
#include <math.h>

// Grid-RNN (WhileOpGridLSTMNet): DEPTH=2, SRC=TRG=32, B=32, H=256
// out[d][i][j][c][b][h], c=0:HX, c=1:HY
#define SRCN 32
#define TRGN 32
#define BN   32
#define HN   256
#define BH   (BN*HN)          // 8192 floats per (cell,channel)
#define CELL (2*BH)           // 16384 floats per cell
#define DSZ  ((size_t)SRCN*TRGN*CELL) // floats per depth
#define NRB  8                // b-rows per chain block
#define NBS  4                // b-slices per (L,i) row

__host__ __device__ __forceinline__ int ncd(int t) { // cells on diag t (0..62)
    int a = t + 1, b = 63 - t;
    int m = a < b ? a : b;
    return m < 32 ? m : 32;
}

// RELAXED RMW poll: executes at the coherence point (L3) -> always fresh
// (r3's stale-L2 relaxed-LOAD hang can't recur), and emits NO cache
// invalidate (r9's ACQUIRE poll invalidated the XCD L2 every poll and
// destroyed weight locality). Producer's RELEASE RMW already ordered its
// sc1 data stores to L3 before the flag; consumer data reads are sc1.
// Bounded: never hangs the harness.
__device__ __forceinline__ void spinwait(int* p) {
    for (int n = 0; n < (1 << 20); ++n) {
        if (__hip_atomic_fetch_add(p, 0, __ATOMIC_RELAXED, __HIP_MEMORY_SCOPE_AGENT) > 0)
            return;
        __builtin_amdgcn_s_sleep(2);
    }
}
// Cross-block state traffic: agent-scope relaxed atomics (sc1) -> L3 direct,
// no L2 pollution/flushes.
__device__ __forceinline__ float cldf(const float* p) {
    return __hip_atomic_load(p, __ATOMIC_RELAXED, __HIP_MEMORY_SCOPE_AGENT);
}
__device__ __forceinline__ void cstf(float* p, float v) {
    __hip_atomic_store(p, v, __ATOMIC_RELAXED, __HIP_MEMORY_SCOPE_AGENT);
}

// ---------------------------------------------------------------------------
// proj0 (proven): xp0[i]=source[i]@W0 ; yp0[j]=target[j]@W0   (into ws)
// ---------------------------------------------------------------------------
__global__ __launch_bounds__(256) void proj0_kernel(
    const float* __restrict__ src, const float* __restrict__ trg,
    const float* __restrict__ W0, float* __restrict__ Xp0, float* __restrict__ Yp0)
{
    __shared__ float xs[BH];
    int blk = blockIdx.x >> 2, tile = blockIdx.x & 3;
    const float* X; float* P;
    if (blk < SRCN) { X = src + blk * BH; P = Xp0 + blk * BH; }
    else            { X = trg + (blk - SRCN) * BH; P = Yp0 + (blk - SRCN) * BH; }
    int tid = threadIdx.x;
    { const float4* x4 = (const float4*)X; float4* s4 = (float4*)xs;
#pragma unroll
      for (int r = 0; r < 8; ++r) s4[tid + r * 256] = x4[tid + r * 256]; }
    __syncthreads();
    int h = tile * 64 + (tid & 63), bg = tid >> 6;
    float acc[8] = {0,0,0,0,0,0,0,0};
    for (int k = 0; k < HN; k += 4) {
        float w0 = W0[(k+0)*HN+h], w1 = W0[(k+1)*HN+h], w2 = W0[(k+2)*HN+h], w3 = W0[(k+3)*HN+h];
#pragma unroll
        for (int bb = 0; bb < 8; ++bb) {
            int b = bg * 8 + bb;
            float4 xv = *(const float4*)&xs[b * HN + k];
            acc[bb] += xv.x*w0 + xv.y*w1 + xv.z*w2 + xv.w*w3;
        }
    }
#pragma unroll
    for (int bb = 0; bb < 8; ++bb) P[(bg*8+bb)*HN + h] = acc[bb];
}

// ---------------------------------------------------------------------------
// chain_kernel: ONE dispatch for both layers.
// block = (L, i, bslice of 8 rows): sweeps j=0..31. j-neighbor state in LDS;
// i-neighbor via flag + sc1 global. proj1 folded into layer-1 cells.
// 256 blocks, 1/CU, all resident. Structure identical to r9 (passed);
// only sync scopes + slicing changed.
// ---------------------------------------------------------------------------
__global__ __launch_bounds__(256, 2) void chain_kernel(
    const float* __restrict__ W, const float* __restrict__ U,
    const float* __restrict__ bias, float* __restrict__ out,
    const float* __restrict__ xp0, const float* __restrict__ yp0,
    int* __restrict__ flg)
{
    __shared__ __align__(16) float sPrev[NRB][HN]; // own HX[i][j-1]
    __shared__ __align__(16) float sUp[NRB][HN];   // HX[i-1][j]
    __shared__ __align__(16) float sX0[NRB][HN];   // l1: HX0[i][j]
    __shared__ __align__(16) float sY0[NRB][HN];   // l1: HY0[i][j]

    const int blk = blockIdx.x;         // 0..255
    const int L   = blk >> 7;           // layer
    const int i   = (blk >> 2) & 31;    // grid row
    const int bs  = blk & (NBS - 1);    // b-slice
    const int r0  = bs * NRB;
    const int h   = threadIdx.x;        // 0..255 = h column

    const float* Ux = U + (size_t)L * 131072 + h; // col h, stride HN over k
    const float* Uy = Ux + 65536;
    const float* W1 = W + 65536 + h;
    const float bv  = bias[L * HN + h];
    float* outL = out + (size_t)L * DSZ;

#pragma unroll
    for (int b = 0; b < NRB; ++b) sPrev[b][h] = 0.f;

    for (int j = 0; j < TRGN; ++j) {
        const int cell = i * TRGN + j;

        // ---- wait for producers (one spinner), then stage via sc1 ----
        if (h == 0) {
            if (i > 0)  spinwait(&flg[((L * 32 + i - 1) * 32 + j) * NBS + bs]);
            if (L == 1) spinwait(&flg[(i * 32 + j) * NBS + bs]); // L0 same cell
        }
        __syncthreads();
        if (i > 0) {
            const float* up = outL + (size_t)((i - 1) * TRGN + j) * CELL
                            + (size_t)r0 * HN + h;
#pragma unroll
            for (int b = 0; b < NRB; ++b) sUp[b][h] = cldf(up + b * HN);
        }
        if (L == 1) {
            const float* x0 = out + (size_t)cell * CELL + (size_t)r0 * HN + h;
#pragma unroll
            for (int b = 0; b < NRB; ++b) {
                sX0[b][h] = cldf(x0 + b * HN);
                sY0[b][h] = cldf(x0 + BH + b * HN);
            }
        }
        __syncthreads();

        // ---- recurrence GEMMs: acc = sUp@Ux + sPrev@Uy (weights L2-hot) ----
        float acc[NRB] = {0.f,0.f,0.f,0.f,0.f,0.f,0.f,0.f};
        if (i > 0) {
            for (int k = 0; k < HN; k += 4) {
                float w0 = Ux[(k+0)*HN], w1 = Ux[(k+1)*HN];
                float w2 = Ux[(k+2)*HN], w3 = Ux[(k+3)*HN];
#pragma unroll
                for (int b = 0; b < NRB; ++b) {
                    float4 s = *(const float4*)&sUp[b][k];   // LDS broadcast
                    acc[b] += s.x*w0 + s.y*w1 + s.z*w2 + s.w*w3;
                }
            }
        }
        if (j > 0) {
            for (int k = 0; k < HN; k += 4) {
                float w0 = Uy[(k+0)*HN], w1 = Uy[(k+1)*HN];
                float w2 = Uy[(k+2)*HN], w3 = Uy[(k+3)*HN];
#pragma unroll
                for (int b = 0; b < NRB; ++b) {
                    float4 s = *(const float4*)&sPrev[b][k]; // LDS broadcast
                    acc[b] += s.x*w0 + s.y*w1 + s.z*w2 + s.w*w3;
                }
            }
        }

        // ---- inputs xp/yp and tanh epilogue ----
        float hx[NRB], hy[NRB];
        if (L == 0) {
            const float* xr = xp0 + (size_t)i * BH + (size_t)r0 * HN + h;
            const float* yr = yp0 + (size_t)j * BH + (size_t)r0 * HN + h;
#pragma unroll
            for (int b = 0; b < NRB; ++b) {
                float tmp = acc[b] + bv;
                hx[b] = tanhf(xr[b * HN] + tmp);
                hy[b] = tanhf(yr[b * HN] + tmp);
            }
        } else {
            // folded proj1: aX = HX0@W1, aY = HY0@W1 (shared W1 loads)
            float aX[NRB] = {0.f,0.f,0.f,0.f,0.f,0.f,0.f,0.f};
            float aY[NRB] = {0.f,0.f,0.f,0.f,0.f,0.f,0.f,0.f};
            for (int k = 0; k < HN; k += 4) {
                float w0 = W1[(k+0)*HN], w1 = W1[(k+1)*HN];
                float w2 = W1[(k+2)*HN], w3 = W1[(k+3)*HN];
#pragma unroll
                for (int b = 0; b < NRB; ++b) {
                    float4 sx4 = *(const float4*)&sX0[b][k];
                    float4 sy4 = *(const float4*)&sY0[b][k];
                    aX[b] += sx4.x*w0 + sx4.y*w1 + sx4.z*w2 + sx4.w*w3;
                    aY[b] += sy4.x*w0 + sy4.y*w1 + sy4.z*w2 + sy4.w*w3;
                }
            }
#pragma unroll
            for (int b = 0; b < NRB; ++b) {
                float tmp = acc[b] + bv;
                hx[b] = tanhf(aX[b] + tmp);
                hy[b] = tanhf(aY[b] + tmp);
            }
        }

        __syncthreads();  // everyone done READING sPrev before overwrite
        float* ox = outL + (size_t)cell * CELL + (size_t)r0 * HN + h;
#pragma unroll
        for (int b = 0; b < NRB; ++b) {
            cstf(ox + b * HN, hx[b]);         // sc1: lands at L3
            cstf(ox + BH + b * HN, hy[b]);
            sPrev[b][h] = hx[b];              // j-neighbor for next cell
        }
        __syncthreads();  // all threads' stores issued before flag
        if (h == 0)       // RELEASE: drains sc1 stores to L3, then bumps flag
            __hip_atomic_fetch_add(&flg[((L * 32 + i) * 32 + j) * NBS + bs], 1,
                                   __ATOMIC_RELEASE, __HIP_MEMORY_SCOPE_AGENT);
    }
}

// ===========================================================================
// Fallback (round-1 ladder, proven): used only if ws_size is too small.
// ===========================================================================
__global__ __launch_bounds__(256) void proj1_kernel(
    float* __restrict__ out, const float* __restrict__ W1)
{
    __shared__ float hxs[BH];
    __shared__ float hys[BH];
    int cell = blockIdx.x >> 2, tile = blockIdx.x & 3;
    const float* hx0 = out + (size_t)cell * CELL;
    const float* hy0 = hx0 + BH;
    float* xp1 = out + DSZ + (size_t)cell * CELL;
    float* yp1 = xp1 + BH;
    int tid = threadIdx.x;
    { const float4* a4 = (const float4*)hx0; const float4* b4 = (const float4*)hy0;
      float4* sa = (float4*)hxs; float4* sb = (float4*)hys;
#pragma unroll
      for (int r = 0; r < 8; ++r) { sa[tid+r*256] = a4[tid+r*256]; sb[tid+r*256] = b4[tid+r*256]; } }
    __syncthreads();
    int h = tile * 64 + (tid & 63), bg = tid >> 6;
    float ax[8] = {0,0,0,0,0,0,0,0}, ay[8] = {0,0,0,0,0,0,0,0};
    for (int k = 0; k < HN; k += 4) {
        float w0 = W1[(k+0)*HN+h], w1 = W1[(k+1)*HN+h], w2 = W1[(k+2)*HN+h], w3 = W1[(k+3)*HN+h];
#pragma unroll
        for (int bb = 0; bb < 8; ++bb) {
            int b = bg * 8 + bb;
            float4 xv = *(const float4*)&hxs[b*HN+k];
            float4 yv = *(const float4*)&hys[b*HN+k];
            ax[bb] += xv.x*w0 + xv.y*w1 + xv.z*w2 + xv.w*w3;
            ay[bb] += yv.x*w0 + yv.y*w1 + yv.z*w2 + yv.w*w3;
        }
    }
#pragma unroll
    for (int bb = 0; bb < 8; ++bb) {
        int b = bg * 8 + bb;
        xp1[b*HN+h] = ax[bb]; yp1[b*HN+h] = ay[bb];
    }
}

__global__ __launch_bounds__(256) void diag_kernel(
    float* out, const float* __restrict__ U, const float* __restrict__ bias,
    const float* __restrict__ Xp0, const float* __restrict__ Yp0, int d, int t)
{
    __shared__ float sxs[BH];
    __shared__ float phs[BH];
    int c = blockIdx.x >> 2, tile = blockIdx.x & 3;
    int i0 = t - (TRGN - 1); if (i0 < 0) i0 = 0;
    int i = i0 + c, j = t - i;
    const float* Ux = U + d * (2 * HN * HN);
    const float* Uy = Ux + HN * HN;
    float* outD = out + (size_t)d * DSZ;
    const float* sx = (i > 0) ? outD + (size_t)((i-1)*TRGN + j) * CELL : nullptr;
    const float* ph = (j > 0) ? outD + (size_t)(i*TRGN + (j-1)) * CELL : nullptr;
    float* oHX = outD + (size_t)(i*TRGN + j) * CELL;
    float* oHY = oHX + BH;
    const float* xp = d ? oHX : (Xp0 + i * BH);
    const float* yp = d ? oHY : (Yp0 + j * BH);
    const float* bd = bias + d * HN;
    int tid = threadIdx.x;
    { const float4* s4 = (const float4*)sx; const float4* p4 = (const float4*)ph;
      float4* d1 = (float4*)sxs; float4* d2 = (float4*)phs;
      float4 z = make_float4(0.f,0.f,0.f,0.f);
#pragma unroll
      for (int r = 0; r < 8; ++r) { int idx = tid + r*256; d1[idx] = sx ? s4[idx] : z; d2[idx] = ph ? p4[idx] : z; } }
    __syncthreads();
    int h = tile * 64 + (tid & 63), bg = tid >> 6;
    float acc[8] = {0,0,0,0,0,0,0,0};
    for (int k = 0; k < HN; k += 4) {
        float ux0 = Ux[(k+0)*HN+h], ux1 = Ux[(k+1)*HN+h], ux2 = Ux[(k+2)*HN+h], ux3 = Ux[(k+3)*HN+h];
        float uy0 = Uy[(k+0)*HN+h], uy1 = Uy[(k+1)*HN+h], uy2 = Uy[(k+2)*HN+h], uy3 = Uy[(k+3)*HN+h];
#pragma unroll
        for (int bb = 0; bb < 8; ++bb) {
            int b = bg * 8 + bb;
            float4 sv = *(const float4*)&sxs[b*HN+k];
            float4 pv = *(const float4*)&phs[b*HN+k];
            acc[bb] += sv.x*ux0 + sv.y*ux1 + sv.z*ux2 + sv.w*ux3
                     + pv.x*uy0 + pv.y*uy1 + pv.z*uy2 + pv.w*uy3;
        }
    }
    float bv = bd[h];
#pragma unroll
    for (int bb = 0; bb < 8; ++bb) {
        int b = bg * 8 + bb;
        float temp = acc[bb] + bv;
        oHX[b*HN+h] = tanhf(xp[b*HN+h] + temp);
        oHY[b*HN+h] = tanhf(yp[b*HN+h] + temp);
    }
}

// ===========================================================================
extern "C" void kernel_launch(void* const* d_in, const int* in_sizes, int n_in,
                              void* d_out, int out_size, void* d_ws, size_t ws_size,
                              hipStream_t stream)
{
    const float* source = (const float*)d_in[0];
    const float* target = (const float*)d_in[1];
    const float* W      = (const float*)d_in[2]; // [2][256][256]
    const float* U      = (const float*)d_in[3]; // [2][512][256]
    const float* bias   = (const float*)d_in[4]; // [2][1][256]
    float* out = (float*)d_out;

    // ws layout: xp0 [1MB] | yp0 [1MB] | flags [32KB]
    const size_t need = 2u * 1024 * 1024 + 32768;
    if (d_ws != nullptr && ws_size >= need) {
        float* xp0 = (float*)d_ws;
        float* yp0 = xp0 + 32 * BH;
        int*   flg = (int*)(yp0 + 32 * BH);
        hipMemsetAsync(flg, 0, 2 * 32 * 32 * NBS * sizeof(int), stream);
        proj0_kernel<<<dim3(64 * 4), dim3(256), 0, stream>>>(source, target, W, xp0, yp0);
        chain_kernel<<<dim3(2 * 32 * NBS), dim3(256), 0, stream>>>(
            W, U, bias, out, xp0, yp0, flg);
    } else {
        // Proven round-1 ladder (scratch aliased into out[1] region; safe
        // because proj1 runs only after ALL layer-0 diagonals).
        float* Xp0 = out + DSZ;
        float* Yp0 = Xp0 + SRCN * BH;
        proj0_kernel<<<dim3(64 * 4), dim3(256), 0, stream>>>(source, target, W, Xp0, Yp0);
        for (int t = 0; t < SRCN + TRGN - 1; ++t) {
            int nc = ncd(t);
            diag_kernel<<<dim3(nc * 4), dim3(256), 0, stream>>>(out, U, bias, Xp0, Yp0, 0, t);
        }
        proj1_kernel<<<dim3(1024 * 4), dim3(256), 0, stream>>>(out, W + HN * HN);
        for (int t = 0; t < SRCN + TRGN - 1; ++t) {
            int nc = ncd(t);
            diag_kernel<<<dim3(nc * 4), dim3(256), 0, stream>>>(out, U, bias, nullptr, nullptr, 1, t);
        }
    }
}

// Round 11
// 2370.574 us; speedup vs baseline: 1.9614x; 1.1342x over previous
//
#include <hip/hip_runtime.h>
#include <math.h>

// Grid-RNN (WhileOpGridLSTMNet): DEPTH=2, SRC=TRG=32, B=32, H=256
// out[d][i][j][c][b][h], c=0:HX, c=1:HY
#define SRCN 32
#define TRGN 32
#define BN   32
#define HN   256
#define BH   (BN*HN)          // 8192 floats per (cell,channel)
#define CELL (2*BH)           // 16384 floats per cell
#define DSZ  ((size_t)SRCN*TRGN*CELL) // floats per depth
#define NRB  8                // b-rows per chain block
#define NBS  4                // b-slices per (L,i) row

__host__ __device__ __forceinline__ int ncd(int t) { // cells on diag t (0..62)
    int a = t + 1, b = 63 - t;
    int m = a < b ? a : b;
    return m < 32 ? m : 32;
}

// RELAXED RMW poll (r10-validated): executes at the coherence point -> always
// fresh, emits no cache invalidate (keeps weights L2-hot). Bounded.
__device__ __forceinline__ void spinwait(int* p) {
    for (int n = 0; n < (1 << 20); ++n) {
        if (__hip_atomic_fetch_add(p, 0, __ATOMIC_RELAXED, __HIP_MEMORY_SCOPE_AGENT) > 0)
            return;
        __builtin_amdgcn_s_sleep(2);
    }
}
// Cross-block state traffic: agent-scope relaxed atomics (sc1) -> L3 direct.
__device__ __forceinline__ float cldf(const float* p) {
    return __hip_atomic_load(p, __ATOMIC_RELAXED, __HIP_MEMORY_SCOPE_AGENT);
}
__device__ __forceinline__ void cstf(float* p, float v) {
    __hip_atomic_store(p, v, __ATOMIC_RELAXED, __HIP_MEMORY_SCOPE_AGENT);
}

// ---------------------------------------------------------------------------
// proj0 (proven): xp0[i]=source[i]@W0 ; yp0[j]=target[j]@W0   (into ws)
// ---------------------------------------------------------------------------
__global__ __launch_bounds__(256) void proj0_kernel(
    const float* __restrict__ src, const float* __restrict__ trg,
    const float* __restrict__ W0, float* __restrict__ Xp0, float* __restrict__ Yp0)
{
    __shared__ float xs[BH];
    int blk = blockIdx.x >> 2, tile = blockIdx.x & 3;
    const float* X; float* P;
    if (blk < SRCN) { X = src + blk * BH; P = Xp0 + blk * BH; }
    else            { X = trg + (blk - SRCN) * BH; P = Yp0 + (blk - SRCN) * BH; }
    int tid = threadIdx.x;
    { const float4* x4 = (const float4*)X; float4* s4 = (float4*)xs;
#pragma unroll
      for (int r = 0; r < 8; ++r) s4[tid + r * 256] = x4[tid + r * 256]; }
    __syncthreads();
    int h = tile * 64 + (tid & 63), bg = tid >> 6;
    float acc[8] = {0,0,0,0,0,0,0,0};
    for (int k = 0; k < HN; k += 4) {
        float w0 = W0[(k+0)*HN+h], w1 = W0[(k+1)*HN+h], w2 = W0[(k+2)*HN+h], w3 = W0[(k+3)*HN+h];
#pragma unroll
        for (int bb = 0; bb < 8; ++bb) {
            int b = bg * 8 + bb;
            float4 xv = *(const float4*)&xs[b * HN + k];
            acc[bb] += xv.x*w0 + xv.y*w1 + xv.z*w2 + xv.w*w3;
        }
    }
#pragma unroll
    for (int bb = 0; bb < 8; ++bb) P[(bg*8+bb)*HN + h] = acc[bb];
}

// ---------------------------------------------------------------------------
// chain2_kernel: ONE dispatch, both layers. block = (L, i, bslice of 8 rows),
// 512 threads = (h, K-half): K-split halves per-wave latency exposure and
// doubles waves/SIMD (2). Partials combined via LDS reduce. L1 releases its
// flag right after HX (HY GEMM deferred off the critical path).
// ---------------------------------------------------------------------------
__global__ __launch_bounds__(512, 1) void chain2_kernel(
    const float* __restrict__ W, const float* __restrict__ U,
    const float* __restrict__ bias, float* __restrict__ out,
    const float* __restrict__ xp0, const float* __restrict__ yp0,
    int* __restrict__ flg)
{
    __shared__ __align__(16) float sPrev[NRB][HN]; // own HX[i][j-1]
    __shared__ __align__(16) float sUp[NRB][HN];   // HX[i-1][j] / aX reduce
    __shared__ __align__(16) float sX0[NRB][HN];   // L1: HX0[i][j]
    __shared__ __align__(16) float sY0[NRB][HN];   // L1: HY0[i][j]
    __shared__ __align__(16) float red[NRB][HN];   // reduce buffer

    const int blk = blockIdx.x;         // 0..255
    const int L   = blk >> 7;
    const int i   = (blk >> 2) & 31;
    const int bs  = blk & (NBS - 1);
    const int r0  = bs * NRB;
    const int tid = threadIdx.x;        // 0..511
    const int h   = tid & 255;          // h column
    const int kh  = tid >> 8;           // K-half 0/1
    const int kof = kh * 128;

    const float* UxB = U + (size_t)L * 131072 + (size_t)kof * HN + h;
    const float* UyB = UxB + 65536;
    const float* W1B = W + 65536 + (size_t)kof * HN + h;
    const float bv   = bias[L * HN + h];
    float* outL = out + (size_t)L * DSZ;
    int* flgL   = flg + L * 4096;

#pragma unroll
    for (int bb = 0; bb < 4; ++bb) sPrev[kh * 4 + bb][h] = 0.f;

    for (int j = 0; j < TRGN; ++j) {
        const int cell = i * TRGN + j;

        // ---- wait for producers, then stage via sc1 ----
        if (tid == 0) {
            if (i > 0)  spinwait(&flgL[((i - 1) * 32 + j) * NBS + bs]);
            if (L == 1) spinwait(&flg[cell * NBS + bs]);  // L0 full-cell flag
        }
        __syncthreads();
        if (i > 0) {
            const float* up = outL + (size_t)((i - 1) * TRGN + j) * CELL
                            + (size_t)r0 * HN + h;
#pragma unroll
            for (int bb = 0; bb < 4; ++bb) {
                int b = kh * 4 + bb;
                sUp[b][h] = cldf(up + b * HN);
            }
        }
        if (L == 1) {
            const float* x0 = out + (size_t)cell * CELL + (size_t)r0 * HN + h;
#pragma unroll
            for (int bb = 0; bb < 4; ++bb) {
                int b = kh * 4 + bb;
                sX0[b][h] = cldf(x0 + b * HN);
                sY0[b][h] = cldf(x0 + BH + b * HN);
            }
        }
        __syncthreads();

        // ---- GEMM partials over this thread's K-half ----
        float acc[NRB] = {0.f,0.f,0.f,0.f,0.f,0.f,0.f,0.f};
        if (i > 0) {
            for (int k = 0; k < 128; k += 4) {
                float w0 = UxB[(k+0)*HN], w1 = UxB[(k+1)*HN];
                float w2 = UxB[(k+2)*HN], w3 = UxB[(k+3)*HN];
#pragma unroll
                for (int b = 0; b < NRB; ++b) {
                    float4 s = *(const float4*)&sUp[b][kof + k];
                    acc[b] += s.x*w0 + s.y*w1 + s.z*w2 + s.w*w3;
                }
            }
        }
        if (j > 0) {
            for (int k = 0; k < 128; k += 4) {
                float w0 = UyB[(k+0)*HN], w1 = UyB[(k+1)*HN];
                float w2 = UyB[(k+2)*HN], w3 = UyB[(k+3)*HN];
#pragma unroll
                for (int b = 0; b < NRB; ++b) {
                    float4 s = *(const float4*)&sPrev[b][kof + k];
                    acc[b] += s.x*w0 + s.y*w1 + s.z*w2 + s.w*w3;
                }
            }
        }
        float aX[NRB] = {0.f,0.f,0.f,0.f,0.f,0.f,0.f,0.f};
        if (L == 1) {
            for (int k = 0; k < 128; k += 4) {
                float w0 = W1B[(k+0)*HN], w1 = W1B[(k+1)*HN];
                float w2 = W1B[(k+2)*HN], w3 = W1B[(k+3)*HN];
#pragma unroll
                for (int b = 0; b < NRB; ++b) {
                    float4 s = *(const float4*)&sX0[b][kof + k];
                    aX[b] += s.x*w0 + s.y*w1 + s.z*w2 + s.w*w3;
                }
            }
        }

        // ---- reduce K-halves (sUp reused as aX reduce buffer) ----
        __syncthreads();                   // all LDS reads of this cell done
        if (kh == 1) {
#pragma unroll
            for (int b = 0; b < NRB; ++b) {
                red[b][h] = acc[b];
                if (L == 1) sUp[b][h] = aX[b];
            }
        }
        __syncthreads();

        // ---- HX (and L0's HY) epilogue by kh==0 half ----
        float temp[NRB];
        if (kh == 0) {
            float* ox = outL + (size_t)cell * CELL + (size_t)r0 * HN + h;
            if (L == 0) {
                const float* xr = xp0 + (size_t)i * BH + (size_t)r0 * HN + h;
                const float* yr = yp0 + (size_t)j * BH + (size_t)r0 * HN + h;
#pragma unroll
                for (int b = 0; b < NRB; ++b) {
                    float tp = acc[b] + red[b][h] + bv;
                    float hx = tanhf(xr[b * HN] + tp);
                    float hy = tanhf(yr[b * HN] + tp);
                    cstf(ox + b * HN, hx);
                    cstf(ox + BH + b * HN, hy);
                    sPrev[b][h] = hx;
                }
            } else {
#pragma unroll
                for (int b = 0; b < NRB; ++b) {
                    float tp = acc[b] + red[b][h] + bv;
                    temp[b] = tp;
                    float hx = tanhf(aX[b] + sUp[b][h] + tp);
                    cstf(ox + b * HN, hx);
                    sPrev[b][h] = hx;
                }
            }
        }
        __syncthreads();   // stores drained (vmcnt0 at barrier), sPrev visible
        if (tid == 0)      // RELEASE orders the flag after the data
            __hip_atomic_fetch_add(&flgL[cell * NBS + bs], 1,
                                   __ATOMIC_RELEASE, __HIP_MEMORY_SCOPE_AGENT);

        // ---- L1 deferred HY (off critical path; no consumer in-kernel) ----
        if (L == 1) {
            float aY[NRB] = {0.f,0.f,0.f,0.f,0.f,0.f,0.f,0.f};
            for (int k = 0; k < 128; k += 4) {
                float w0 = W1B[(k+0)*HN], w1 = W1B[(k+1)*HN];
                float w2 = W1B[(k+2)*HN], w3 = W1B[(k+3)*HN];
#pragma unroll
                for (int b = 0; b < NRB; ++b) {
                    float4 s = *(const float4*)&sY0[b][kof + k];
                    aY[b] += s.x*w0 + s.y*w1 + s.z*w2 + s.w*w3;
                }
            }
            if (kh == 1) {
#pragma unroll
                for (int b = 0; b < NRB; ++b) red[b][h] = aY[b];
            }
            __syncthreads();
            if (kh == 0) {
                float* oy = outL + (size_t)cell * CELL + BH + (size_t)r0 * HN + h;
#pragma unroll
                for (int b = 0; b < NRB; ++b)
                    oy[b * HN] = tanhf(aY[b] + red[b][h] + temp[b]); // plain store
            }
        }
    }
}

// ===========================================================================
// Fallback (round-1 ladder, proven): used only if ws_size is too small.
// ===========================================================================
__global__ __launch_bounds__(256) void proj1_kernel(
    float* __restrict__ out, const float* __restrict__ W1)
{
    __shared__ float hxs[BH];
    __shared__ float hys[BH];
    int cell = blockIdx.x >> 2, tile = blockIdx.x & 3;
    const float* hx0 = out + (size_t)cell * CELL;
    const float* hy0 = hx0 + BH;
    float* xp1 = out + DSZ + (size_t)cell * CELL;
    float* yp1 = xp1 + BH;
    int tid = threadIdx.x;
    { const float4* a4 = (const float4*)hx0; const float4* b4 = (const float4*)hy0;
      float4* sa = (float4*)hxs; float4* sb = (float4*)hys;
#pragma unroll
      for (int r = 0; r < 8; ++r) { sa[tid+r*256] = a4[tid+r*256]; sb[tid+r*256] = b4[tid+r*256]; } }
    __syncthreads();
    int h = tile * 64 + (tid & 63), bg = tid >> 6;
    float ax[8] = {0,0,0,0,0,0,0,0}, ay[8] = {0,0,0,0,0,0,0,0};
    for (int k = 0; k < HN; k += 4) {
        float w0 = W1[(k+0)*HN+h], w1 = W1[(k+1)*HN+h], w2 = W1[(k+2)*HN+h], w3 = W1[(k+3)*HN+h];
#pragma unroll
        for (int bb = 0; bb < 8; ++bb) {
            int b = bg * 8 + bb;
            float4 xv = *(const float4*)&hxs[b*HN+k];
            float4 yv = *(const float4*)&hys[b*HN+k];
            ax[bb] += xv.x*w0 + xv.y*w1 + xv.z*w2 + xv.w*w3;
            ay[bb] += yv.x*w0 + yv.y*w1 + yv.z*w2 + yv.w*w3;
        }
    }
#pragma unroll
    for (int bb = 0; bb < 8; ++bb) {
        int b = bg * 8 + bb;
        xp1[b*HN+h] = ax[bb]; yp1[b*HN+h] = ay[bb];
    }
}

__global__ __launch_bounds__(256) void diag_kernel(
    float* out, const float* __restrict__ U, const float* __restrict__ bias,
    const float* __restrict__ Xp0, const float* __restrict__ Yp0, int d, int t)
{
    __shared__ float sxs[BH];
    __shared__ float phs[BH];
    int c = blockIdx.x >> 2, tile = blockIdx.x & 3;
    int i0 = t - (TRGN - 1); if (i0 < 0) i0 = 0;
    int i = i0 + c, j = t - i;
    const float* Ux = U + d * (2 * HN * HN);
    const float* Uy = Ux + HN * HN;
    float* outD = out + (size_t)d * DSZ;
    const float* sx = (i > 0) ? outD + (size_t)((i-1)*TRGN + j) * CELL : nullptr;
    const float* ph = (j > 0) ? outD + (size_t)(i*TRGN + (j-1)) * CELL : nullptr;
    float* oHX = outD + (size_t)(i*TRGN + j) * CELL;
    float* oHY = oHX + BH;
    const float* xp = d ? oHX : (Xp0 + i * BH);
    const float* yp = d ? oHY : (Yp0 + j * BH);
    const float* bd = bias + d * HN;
    int tid = threadIdx.x;
    { const float4* s4 = (const float4*)sx; const float4* p4 = (const float4*)ph;
      float4* d1 = (float4*)sxs; float4* d2 = (float4*)phs;
      float4 z = make_float4(0.f,0.f,0.f,0.f);
#pragma unroll
      for (int r = 0; r < 8; ++r) { int idx = tid + r*256; d1[idx] = sx ? s4[idx] : z; d2[idx] = ph ? p4[idx] : z; } }
    __syncthreads();
    int h = tile * 64 + (tid & 63), bg = tid >> 6;
    float acc[8] = {0,0,0,0,0,0,0,0};
    for (int k = 0; k < HN; k += 4) {
        float ux0 = Ux[(k+0)*HN+h], ux1 = Ux[(k+1)*HN+h], ux2 = Ux[(k+2)*HN+h], ux3 = Ux[(k+3)*HN+h];
        float uy0 = Uy[(k+0)*HN+h], uy1 = Uy[(k+1)*HN+h], uy2 = Uy[(k+2)*HN+h], uy3 = Uy[(k+3)*HN+h];
#pragma unroll
        for (int bb = 0; bb < 8; ++bb) {
            int b = bg * 8 + bb;
            float4 sv = *(const float4*)&sxs[b*HN+k];
            float4 pv = *(const float4*)&phs[b*HN+k];
            acc[bb] += sv.x*ux0 + sv.y*ux1 + sv.z*ux2 + sv.w*ux3
                     + pv.x*uy0 + pv.y*uy1 + pv.z*uy2 + pv.w*uy3;
        }
    }
    float bv = bd[h];
#pragma unroll
    for (int bb = 0; bb < 8; ++bb) {
        int b = bg * 8 + bb;
        float temp = acc[bb] + bv;
        oHX[b*HN+h] = tanhf(xp[b*HN+h] + temp);
        oHY[b*HN+h] = tanhf(yp[b*HN+h] + temp);
    }
}

// ===========================================================================
extern "C" void kernel_launch(void* const* d_in, const int* in_sizes, int n_in,
                              void* d_out, int out_size, void* d_ws, size_t ws_size,
                              hipStream_t stream)
{
    const float* source = (const float*)d_in[0];
    const float* target = (const float*)d_in[1];
    const float* W      = (const float*)d_in[2]; // [2][256][256]
    const float* U      = (const float*)d_in[3]; // [2][512][256]
    const float* bias   = (const float*)d_in[4]; // [2][1][256]
    float* out = (float*)d_out;

    // ws layout: xp0 [1MB] | yp0 [1MB] | flags [32KB]
    const size_t need = 2u * 1024 * 1024 + 32768;
    if (d_ws != nullptr && ws_size >= need) {
        float* xp0 = (float*)d_ws;
        float* yp0 = xp0 + 32 * BH;
        int*   flg = (int*)(yp0 + 32 * BH);
        hipMemsetAsync(flg, 0, 2 * 32 * 32 * NBS * sizeof(int), stream);
        proj0_kernel<<<dim3(64 * 4), dim3(256), 0, stream>>>(source, target, W, xp0, yp0);
        chain2_kernel<<<dim3(2 * 32 * NBS), dim3(512), 0, stream>>>(
            W, U, bias, out, xp0, yp0, flg);
    } else {
        // Proven round-1 ladder (scratch aliased into out[1] region; safe
        // because proj1 runs only after ALL layer-0 diagonals).
        float* Xp0 = out + DSZ;
        float* Yp0 = Xp0 + SRCN * BH;
        proj0_kernel<<<dim3(64 * 4), dim3(256), 0, stream>>>(source, target, W, Xp0, Yp0);
        for (int t = 0; t < SRCN + TRGN - 1; ++t) {
            int nc = ncd(t);
            diag_kernel<<<dim3(nc * 4), dim3(256), 0, stream>>>(out, U, bias, Xp0, Yp0, 0, t);
        }
        proj1_kernel<<<dim3(1024 * 4), dim3(256), 0, stream>>>(out, W + HN * HN);
        for (int t = 0; t < SRCN + TRGN - 1; ++t) {
            int nc = ncd(t);
            diag_kernel<<<dim3(nc * 4), dim3(256), 0, stream>>>(out, U, bias, nullptr, nullptr, 1, t);
        }
    }
}

// Round 12
// 1581.817 us; speedup vs baseline: 2.9394x; 1.4986x over previous
//
#include <hip/hip_runtime.h>
#include <math.h>

// Grid-RNN (WhileOpGridLSTMNet): DEPTH=2, SRC=TRG=32, B=32, H=256
// out[d][i][j][c][b][h], c=0:HX, c=1:HY
#define SRCN 32
#define TRGN 32
#define BN   32
#define HN   256
#define BH   (BN*HN)          // 8192 floats per (cell,channel)
#define CELL (2*BH)           // 16384 floats per cell
#define DSZ  ((size_t)SRCN*TRGN*CELL) // floats per depth
#define NRB  8                // b-rows per chain block
#define NBS  4                // b-slices per (L,i) row

__host__ __device__ __forceinline__ int ncd(int t) { // cells on diag t (0..62)
    int a = t + 1, b = 63 - t;
    int m = a < b ? a : b;
    return m < 32 ? m : 32;
}

// RELAXED RMW poll (r10/r11-validated): coherence-point read, no invalidate.
__device__ __forceinline__ void spinwait(int* p) {
    for (int n = 0; n < (1 << 20); ++n) {
        if (__hip_atomic_fetch_add(p, 0, __ATOMIC_RELAXED, __HIP_MEMORY_SCOPE_AGENT) > 0)
            return;
        __builtin_amdgcn_s_sleep(2);
    }
}
__device__ __forceinline__ float cldf(const float* p) {
    return __hip_atomic_load(p, __ATOMIC_RELAXED, __HIP_MEMORY_SCOPE_AGENT);
}
__device__ __forceinline__ void cstf(float* p, float v) {
    __hip_atomic_store(p, v, __ATOMIC_RELAXED, __HIP_MEMORY_SCOPE_AGENT);
}

// ---------------------------------------------------------------------------
// proj0 (proven): xp0[i]=source[i]@W0 ; yp0[j]=target[j]@W0   (into ws)
// ---------------------------------------------------------------------------
__global__ __launch_bounds__(256) void proj0_kernel(
    const float* __restrict__ src, const float* __restrict__ trg,
    const float* __restrict__ W0, float* __restrict__ Xp0, float* __restrict__ Yp0)
{
    __shared__ float xs[BH];
    int blk = blockIdx.x >> 2, tile = blockIdx.x & 3;
    const float* X; float* P;
    if (blk < SRCN) { X = src + blk * BH; P = Xp0 + blk * BH; }
    else            { X = trg + (blk - SRCN) * BH; P = Yp0 + (blk - SRCN) * BH; }
    int tid = threadIdx.x;
    { const float4* x4 = (const float4*)X; float4* s4 = (float4*)xs;
#pragma unroll
      for (int r = 0; r < 8; ++r) s4[tid + r * 256] = x4[tid + r * 256]; }
    __syncthreads();
    int h = tile * 64 + (tid & 63), bg = tid >> 6;
    float acc[8] = {0,0,0,0,0,0,0,0};
    for (int k = 0; k < HN; k += 4) {
        float w0 = W0[(k+0)*HN+h], w1 = W0[(k+1)*HN+h], w2 = W0[(k+2)*HN+h], w3 = W0[(k+3)*HN+h];
#pragma unroll
        for (int bb = 0; bb < 8; ++bb) {
            int b = bg * 8 + bb;
            float4 xv = *(const float4*)&xs[b * HN + k];
            acc[bb] += xv.x*w0 + xv.y*w1 + xv.z*w2 + xv.w*w3;
        }
    }
#pragma unroll
    for (int bb = 0; bb < 8; ++bb) P[(bg*8+bb)*HN + h] = acc[bb];
}

// ---------------------------------------------------------------------------
// chain3_kernel: ONE dispatch, both layers. block = (L, i, bslice of 8 rows),
// 512 threads = (h, K-half). All off-path GEMMs (Uy, W1x, W1y) hoisted
// BEFORE the critical i-neighbor poll; only sUp@Ux + epilogue on-path.
// L1's HY moved after the flag release (no in-kernel consumer).
// ---------------------------------------------------------------------------
__global__ __launch_bounds__(512, 1) void chain3_kernel(
    const float* __restrict__ W, const float* __restrict__ U,
    const float* __restrict__ bias, float* __restrict__ out,
    const float* __restrict__ xp0, const float* __restrict__ yp0,
    int* __restrict__ flg)
{
    __shared__ __align__(16) float sPrev[NRB][HN]; // own HX[i][j-1]
    __shared__ __align__(16) float sUp[NRB][HN];   // HX[i-1][j]
    __shared__ __align__(16) float sX0[NRB][HN];   // L1: HX0[i][j]
    __shared__ __align__(16) float sY0[NRB][HN];   // L1: HY0[i][j]
    __shared__ __align__(16) float redT[NRB][HN];  // temp reduce
    __shared__ __align__(16) float redX[NRB][HN];  // aX reduce
    __shared__ __align__(16) float redY[NRB][HN];  // aY reduce

    const int blk = blockIdx.x;         // 0..255
    const int L   = blk >> 7;
    const int i   = (blk >> 2) & 31;
    const int bs  = blk & (NBS - 1);
    const int r0  = bs * NRB;
    const int tid = threadIdx.x;        // 0..511
    const int h   = tid & 255;          // h column
    const int kh  = tid >> 8;           // K-half 0/1
    const int kof = kh * 128;

    const float* UxB = U + (size_t)L * 131072 + (size_t)kof * HN + h;
    const float* UyB = UxB + 65536;
    const float* W1B = W + 65536 + (size_t)kof * HN + h;
    const float bv   = bias[L * HN + h];
    float* outL = out + (size_t)L * DSZ;
    int* flgL   = flg + L * 4096;

#pragma unroll
    for (int bb = 0; bb < 4; ++bb) sPrev[kh * 4 + bb][h] = 0.f;
    __syncthreads();

    for (int j = 0; j < TRGN; ++j) {
        const int cell = i * TRGN + j;

        // ================= OFF-PATH PREP (before critical poll) ===========
        if (L == 1) {
            if (tid == 0) spinwait(&flg[cell * NBS + bs]); // L0 flag: long set
            __syncthreads();
            const float* x0 = out + (size_t)cell * CELL + (size_t)r0 * HN + h;
#pragma unroll
            for (int bb = 0; bb < 4; ++bb) {
                int b = kh * 4 + bb;
                sX0[b][h] = cldf(x0 + b * HN);
                sY0[b][h] = cldf(x0 + BH + b * HN);
            }
            __syncthreads();
        }

        float acc[NRB] = {0.f,0.f,0.f,0.f,0.f,0.f,0.f,0.f}; // temp partial
        if (j > 0) {
#pragma unroll 2
            for (int k = 0; k < 128; k += 4) {
                float w0 = UyB[(k+0)*HN], w1 = UyB[(k+1)*HN];
                float w2 = UyB[(k+2)*HN], w3 = UyB[(k+3)*HN];
#pragma unroll
                for (int b = 0; b < NRB; ++b) {
                    float4 s = *(const float4*)&sPrev[b][kof + k];
                    acc[b] += s.x*w0 + s.y*w1 + s.z*w2 + s.w*w3;
                }
            }
        }
        float aX[NRB] = {0.f,0.f,0.f,0.f,0.f,0.f,0.f,0.f};
        float aY[NRB] = {0.f,0.f,0.f,0.f,0.f,0.f,0.f,0.f};
        float xin[NRB], yin[NRB];
        if (L == 1) {
#pragma unroll 2
            for (int k = 0; k < 128; k += 4) {
                float w0 = W1B[(k+0)*HN], w1 = W1B[(k+1)*HN];
                float w2 = W1B[(k+2)*HN], w3 = W1B[(k+3)*HN];
#pragma unroll
                for (int b = 0; b < NRB; ++b) {
                    float4 sx4 = *(const float4*)&sX0[b][kof + k];
                    float4 sy4 = *(const float4*)&sY0[b][kof + k];
                    aX[b] += sx4.x*w0 + sx4.y*w1 + sx4.z*w2 + sx4.w*w3;
                    aY[b] += sy4.x*w0 + sy4.y*w1 + sy4.z*w2 + sy4.w*w3;
                }
            }
        } else if (kh == 0) {
            const float* xr = xp0 + (size_t)i * BH + (size_t)r0 * HN + h;
            const float* yr = yp0 + (size_t)j * BH + (size_t)r0 * HN + h;
#pragma unroll
            for (int b = 0; b < NRB; ++b) {
                xin[b] = xr[b * HN];
                yin[b] = yr[b * HN];
            }
        }

        // ================= ON-PATH ========================================
        if (tid == 0 && i > 0) spinwait(&flgL[((i - 1) * 32 + j) * NBS + bs]);
        __syncthreads();   // flag barrier; also fences red* reuse
        if (i > 0) {
            const float* up = outL + (size_t)((i - 1) * TRGN + j) * CELL
                            + (size_t)r0 * HN + h;
#pragma unroll
            for (int bb = 0; bb < 4; ++bb) {
                int b = kh * 4 + bb;
                sUp[b][h] = cldf(up + b * HN);
            }
            __syncthreads();
#pragma unroll 2
            for (int k = 0; k < 128; k += 4) {
                float w0 = UxB[(k+0)*HN], w1 = UxB[(k+1)*HN];
                float w2 = UxB[(k+2)*HN], w3 = UxB[(k+3)*HN];
#pragma unroll
                for (int b = 0; b < NRB; ++b) {
                    float4 s = *(const float4*)&sUp[b][kof + k];
                    acc[b] += s.x*w0 + s.y*w1 + s.z*w2 + s.w*w3;
                }
            }
        }

        // reduce K-halves
        if (kh == 1) {
#pragma unroll
            for (int b = 0; b < NRB; ++b) {
                redT[b][h] = acc[b];
                if (L == 1) { redX[b][h] = aX[b]; redY[b][h] = aY[b]; }
            }
        }
        __syncthreads();

        float temp[NRB];
        if (kh == 0) {
            float* ox = outL + (size_t)cell * CELL + (size_t)r0 * HN + h;
            if (L == 0) {
#pragma unroll
                for (int b = 0; b < NRB; ++b) {
                    float tp = acc[b] + redT[b][h] + bv;
                    float hx = tanhf(xin[b] + tp);
                    float hy = tanhf(yin[b] + tp);
                    cstf(ox + b * HN, hx);           // consumed by L1/chain
                    cstf(ox + BH + b * HN, hy);      // consumed by L1
                    sPrev[b][h] = hx;
                }
            } else {
#pragma unroll
                for (int b = 0; b < NRB; ++b) {
                    float tp = acc[b] + redT[b][h] + bv;
                    temp[b] = tp;
                    float hx = tanhf(aX[b] + redX[b][h] + tp);
                    cstf(ox + b * HN, hx);           // consumed down-chain
                    sPrev[b][h] = hx;
                }
            }
        }
        __syncthreads();   // stores drained + sPrev visible before flag
        if (tid == 0)
            __hip_atomic_fetch_add(&flgL[cell * NBS + bs], 1,
                                   __ATOMIC_RELEASE, __HIP_MEMORY_SCOPE_AGENT);

        // ================= POST-PATH: L1's HY (no in-kernel consumer) =====
        if (L == 1 && kh == 0) {
            float* oy = outL + (size_t)cell * CELL + BH + (size_t)r0 * HN + h;
#pragma unroll
            for (int b = 0; b < NRB; ++b)
                oy[b * HN] = tanhf(aY[b] + redY[b][h] + temp[b]); // plain store
        }
        // redY read-after-release is fenced from next j's writes by the L1
        // L0-flag barrier (L1 always executes it).
    }
}

// ===========================================================================
// Fallback (round-1 ladder, proven): used only if ws_size is too small.
// ===========================================================================
__global__ __launch_bounds__(256) void proj1_kernel(
    float* __restrict__ out, const float* __restrict__ W1)
{
    __shared__ float hxs[BH];
    __shared__ float hys[BH];
    int cell = blockIdx.x >> 2, tile = blockIdx.x & 3;
    const float* hx0 = out + (size_t)cell * CELL;
    const float* hy0 = hx0 + BH;
    float* xp1 = out + DSZ + (size_t)cell * CELL;
    float* yp1 = xp1 + BH;
    int tid = threadIdx.x;
    { const float4* a4 = (const float4*)hx0; const float4* b4 = (const float4*)hy0;
      float4* sa = (float4*)hxs; float4* sb = (float4*)hys;
#pragma unroll
      for (int r = 0; r < 8; ++r) { sa[tid+r*256] = a4[tid+r*256]; sb[tid+r*256] = b4[tid+r*256]; } }
    __syncthreads();
    int h = tile * 64 + (tid & 63), bg = tid >> 6;
    float ax[8] = {0,0,0,0,0,0,0,0}, ay[8] = {0,0,0,0,0,0,0,0};
    for (int k = 0; k < HN; k += 4) {
        float w0 = W1[(k+0)*HN+h], w1 = W1[(k+1)*HN+h], w2 = W1[(k+2)*HN+h], w3 = W1[(k+3)*HN+h];
#pragma unroll
        for (int bb = 0; bb < 8; ++bb) {
            int b = bg * 8 + bb;
            float4 xv = *(const float4*)&hxs[b*HN+k];
            float4 yv = *(const float4*)&hys[b*HN+k];
            ax[bb] += xv.x*w0 + xv.y*w1 + xv.z*w2 + xv.w*w3;
            ay[bb] += yv.x*w0 + yv.y*w1 + yv.z*w2 + yv.w*w3;
        }
    }
#pragma unroll
    for (int bb = 0; bb < 8; ++bb) {
        int b = bg * 8 + bb;
        xp1[b*HN+h] = ax[bb]; yp1[b*HN+h] = ay[bb];
    }
}

__global__ __launch_bounds__(256) void diag_kernel(
    float* out, const float* __restrict__ U, const float* __restrict__ bias,
    const float* __restrict__ Xp0, const float* __restrict__ Yp0, int d, int t)
{
    __shared__ float sxs[BH];
    __shared__ float phs[BH];
    int c = blockIdx.x >> 2, tile = blockIdx.x & 3;
    int i0 = t - (TRGN - 1); if (i0 < 0) i0 = 0;
    int i = i0 + c, j = t - i;
    const float* Ux = U + d * (2 * HN * HN);
    const float* Uy = Ux + HN * HN;
    float* outD = out + (size_t)d * DSZ;
    const float* sx = (i > 0) ? outD + (size_t)((i-1)*TRGN + j) * CELL : nullptr;
    const float* ph = (j > 0) ? outD + (size_t)(i*TRGN + (j-1)) * CELL : nullptr;
    float* oHX = outD + (size_t)(i*TRGN + j) * CELL;
    float* oHY = oHX + BH;
    const float* xp = d ? oHX : (Xp0 + i * BH);
    const float* yp = d ? oHY : (Yp0 + j * BH);
    const float* bd = bias + d * HN;
    int tid = threadIdx.x;
    { const float4* s4 = (const float4*)sx; const float4* p4 = (const float4*)ph;
      float4* d1 = (float4*)sxs; float4* d2 = (float4*)phs;
      float4 z = make_float4(0.f,0.f,0.f,0.f);
#pragma unroll
      for (int r = 0; r < 8; ++r) { int idx = tid + r*256; d1[idx] = sx ? s4[idx] : z; d2[idx] = ph ? p4[idx] : z; } }
    __syncthreads();
    int h = tile * 64 + (tid & 63), bg = tid >> 6;
    float acc[8] = {0,0,0,0,0,0,0,0};
    for (int k = 0; k < HN; k += 4) {
        float ux0 = Ux[(k+0)*HN+h], ux1 = Ux[(k+1)*HN+h], ux2 = Ux[(k+2)*HN+h], ux3 = Ux[(k+3)*HN+h];
        float uy0 = Uy[(k+0)*HN+h], uy1 = Uy[(k+1)*HN+h], uy2 = Uy[(k+2)*HN+h], uy3 = Uy[(k+3)*HN+h];
#pragma unroll
        for (int bb = 0; bb < 8; ++bb) {
            int b = bg * 8 + bb;
            float4 sv = *(const float4*)&sxs[b*HN+k];
            float4 pv = *(const float4*)&phs[b*HN+k];
            acc[bb] += sv.x*ux0 + sv.y*ux1 + sv.z*ux2 + sv.w*ux3
                     + pv.x*uy0 + pv.y*uy1 + pv.z*uy2 + pv.w*uy3;
        }
    }
    float bv = bd[h];
#pragma unroll
    for (int bb = 0; bb < 8; ++bb) {
        int b = bg * 8 + bb;
        float temp = acc[bb] + bv;
        oHX[b*HN+h] = tanhf(xp[b*HN+h] + temp);
        oHY[b*HN+h] = tanhf(yp[b*HN+h] + temp);
    }
}

// ===========================================================================
extern "C" void kernel_launch(void* const* d_in, const int* in_sizes, int n_in,
                              void* d_out, int out_size, void* d_ws, size_t ws_size,
                              hipStream_t stream)
{
    const float* source = (const float*)d_in[0];
    const float* target = (const float*)d_in[1];
    const float* W      = (const float*)d_in[2]; // [2][256][256]
    const float* U      = (const float*)d_in[3]; // [2][512][256]
    const float* bias   = (const float*)d_in[4]; // [2][1][256]
    float* out = (float*)d_out;

    // ws layout: xp0 [1MB] | yp0 [1MB] | flags [32KB]
    const size_t need = 2u * 1024 * 1024 + 32768;
    if (d_ws != nullptr && ws_size >= need) {
        float* xp0 = (float*)d_ws;
        float* yp0 = xp0 + 32 * BH;
        int*   flg = (int*)(yp0 + 32 * BH);
        hipMemsetAsync(flg, 0, 2 * 32 * 32 * NBS * sizeof(int), stream);
        proj0_kernel<<<dim3(64 * 4), dim3(256), 0, stream>>>(source, target, W, xp0, yp0);
        chain3_kernel<<<dim3(2 * 32 * NBS), dim3(512), 0, stream>>>(
            W, U, bias, out, xp0, yp0, flg);
    } else {
        // Proven round-1 ladder (scratch aliased into out[1] region; safe
        // because proj1 runs only after ALL layer-0 diagonals).
        float* Xp0 = out + DSZ;
        float* Yp0 = Xp0 + SRCN * BH;
        proj0_kernel<<<dim3(64 * 4), dim3(256), 0, stream>>>(source, target, W, Xp0, Yp0);
        for (int t = 0; t < SRCN + TRGN - 1; ++t) {
            int nc = ncd(t);
            diag_kernel<<<dim3(nc * 4), dim3(256), 0, stream>>>(out, U, bias, Xp0, Yp0, 0, t);
        }
        proj1_kernel<<<dim3(1024 * 4), dim3(256), 0, stream>>>(out, W + HN * HN);
        for (int t = 0; t < SRCN + TRGN - 1; ++t) {
            int nc = ncd(t);
            diag_kernel<<<dim3(nc * 4), dim3(256), 0, stream>>>(out, U, bias, nullptr, nullptr, 1, t);
        }
    }
}